// Round 1
// baseline (433.649 us; speedup 1.0000x reference)
//
#include <hip/hip_runtime.h>

#define H_NUM 16
#define HD    64
#define SQ    2048
#define BATCH 4
#define HID   1024
#define MTOK  8192   // B*S

typedef __attribute__((ext_vector_type(8))) short bf16x8;
typedef __attribute__((ext_vector_type(4))) short s16x4;
typedef __attribute__((ext_vector_type(4))) float f32x4;

__device__ __forceinline__ short f2bf(float f) {
  union { float f; unsigned u; } v; v.f = f;
  unsigned r = v.u + 0x7fffu + ((v.u >> 16) & 1u);
  return (short)(r >> 16);
}

__device__ __forceinline__ void gload_lds16(const short* g, short* l) {
  __builtin_amdgcn_global_load_lds(
      (const __attribute__((address_space(1))) void*)g,
      (__attribute__((address_space(3))) void*)l, 16, 0, 0);
}

// ---------- converters ----------
__global__ void k_cvt(const float* __restrict__ in, short* __restrict__ out, int n4) {
  int i = blockIdx.x * blockDim.x + threadIdx.x;
  if (i < n4) {
    float4 f = ((const float4*)in)[i];
    s16x4 o = { f2bf(f.x), f2bf(f.y), f2bf(f.z), f2bf(f.w) };
    ((s16x4*)out)[i] = o;
  }
}

// out[c][r] = bf16(in[r][c]);  R,C multiples of 32; block (32,8)
__global__ void k_tr(const float* __restrict__ in, short* __restrict__ out, int R, int C) {
  __shared__ float t[32][33];
  int c0 = blockIdx.x * 32, r0 = blockIdx.y * 32;
  int tx = threadIdx.x, ty = threadIdx.y;
#pragma unroll
  for (int i = 0; i < 4; i++)
    t[ty + 8 * i][tx] = in[(size_t)(r0 + ty + 8 * i) * C + c0 + tx];
  __syncthreads();
#pragma unroll
  for (int i = 0; i < 4; i++)
    out[(size_t)(c0 + ty + 8 * i) * R + r0 + tx] = f2bf(t[tx][ty + 8 * i]);
}

// ---------- GEMM: C[M,N] = A[M,K] @ Bt[N,K]^T + bias ----------
// EPI=0: scatter into k/vt/q buffers (col order: k, v, q; q scaled 1/8)
// EPI=1: f32 out with bias
template <int EPI>
__global__ __launch_bounds__(256) void k_gemm(
    const short* __restrict__ A, const short* __restrict__ Bt,
    const float* __restrict__ bias,
    short* __restrict__ qbuf, short* __restrict__ kbuf, short* __restrict__ vtbuf,
    float* __restrict__ outf, int Kd) {
  __shared__ short as[128][64];
  __shared__ short bs[128][64];
  const int tid = threadIdx.x;
  const int w = tid >> 6, l = tid & 63;
  const int lr = l & 15, lk = l >> 4;
  const int wr = w >> 1, wc = w & 1;
  const int m0 = blockIdx.y * 128, n0 = blockIdx.x * 128;

  f32x4 acc[4][4] = {};

  for (int kt = 0; kt < Kd; kt += 64) {
    // stage A-tile and Bt-tile, 16B/lane via global_load_lds (linear LDS)
#pragma unroll
    for (int rnd = 0; rnd < 4; ++rnd) {
      int e = rnd * 2048 + w * 512 + l * 8;  // element index within tile
      int row = e >> 6, col = e & 63;
      gload_lds16(A + (size_t)(m0 + row) * Kd + kt + col,
                  &as[0][0] + rnd * 2048 + w * 512);
      gload_lds16(Bt + (size_t)(n0 + row) * Kd + kt + col,
                  &bs[0][0] + rnd * 2048 + w * 512);
    }
    __syncthreads();
#pragma unroll
    for (int kk = 0; kk < 2; ++kk) {
      bf16x8 af[4], bf[4];
#pragma unroll
      for (int m = 0; m < 4; ++m)
        af[m] = *(const bf16x8*)&as[wr * 64 + m * 16 + lr][kk * 32 + lk * 8];
#pragma unroll
      for (int n = 0; n < 4; ++n)
        bf[n] = *(const bf16x8*)&bs[wc * 64 + n * 16 + lr][kk * 32 + lk * 8];
#pragma unroll
      for (int m = 0; m < 4; ++m)
#pragma unroll
        for (int n = 0; n < 4; ++n)
          acc[m][n] = __builtin_amdgcn_mfma_f32_16x16x32_bf16(af[m], bf[n], acc[m][n], 0, 0, 0);
    }
    __syncthreads();
  }

  // epilogue: C layout col=lane&15, row=(lane>>4)*4+reg   [measured m89]
#pragma unroll
  for (int m = 0; m < 4; ++m)
#pragma unroll
    for (int n = 0; n < 4; ++n)
#pragma unroll
      for (int r = 0; r < 4; ++r) {
        int row = m0 + wr * 64 + m * 16 + lk * 4 + r;
        int col = n0 + wc * 64 + n * 16 + lr;
        float v = acc[m][n][r] + bias[col];
        if (EPI == 0) {
          int b = row >> 11, s = row & 2047;
          if (col < HID) {  // K: [BH][S][D]
            int h = col >> 6, d = col & 63;
            kbuf[((size_t)(b * H_NUM + h) * SQ + s) * HD + d] = f2bf(v);
          } else if (col < 2 * HID) {  // V transposed: [BH][D][S]
            int f = col - HID, h = f >> 6, d = f & 63;
            vtbuf[((size_t)(b * H_NUM + h) * HD + d) * SQ + s] = f2bf(v);
          } else {  // Q: [BH][S][D], scaled by HEAD_DIM^-0.5
            int f = col - 2 * HID, h = f >> 6, d = f & 63;
            qbuf[((size_t)(b * H_NUM + h) * SQ + s) * HD + d] = f2bf(v * 0.125f);
          }
        } else {
          outf[(size_t)row * HID + col] = v;
        }
      }
}

// ---------- flash attention, causal ----------
// grid: (S/64, B*H), block 256 (4 waves x 16 q-rows)
__global__ __launch_bounds__(256) void k_attn(
    const short* __restrict__ Q, const short* __restrict__ K,
    const short* __restrict__ Vt, short* __restrict__ ctx) {
  __shared__ short ks[64][64];
  __shared__ short vts[64][64];   // [d][k]
  __shared__ short ps[4][16][64]; // per-wave P buffer
  const int tid = threadIdx.x;
  const int w = tid >> 6, l = tid & 63;
  const int lr = l & 15, lk = l >> 4;
  const int qt = blockIdx.x, bh = blockIdx.y;
  const size_t base = (size_t)bh * SQ * HD;

  const int qrow = qt * 64 + w * 16 + lr;
  bf16x8 qf[2];
#pragma unroll
  for (int kk = 0; kk < 2; ++kk)
    qf[kk] = *(const bf16x8*)(Q + base + (size_t)qrow * HD + kk * 32 + lk * 8);

  f32x4 o[4] = {};
  float mrun[4], lsum[4];
#pragma unroll
  for (int r = 0; r < 4; ++r) { mrun[r] = -1e30f; lsum[r] = 0.f; }

  for (int t = 0; t <= qt; ++t) {
#pragma unroll
    for (int rnd = 0; rnd < 2; ++rnd) {
      int e = rnd * 2048 + w * 512 + l * 8;
      int row = e >> 6, col = e & 63;
      gload_lds16(K + base + (size_t)(t * 64 + row) * HD + col,
                  &ks[0][0] + rnd * 2048 + w * 512);
      gload_lds16(Vt + base + (size_t)row * SQ + t * 64 + col,
                  &vts[0][0] + rnd * 2048 + w * 512);
    }
    __syncthreads();

    // S = Q @ K^T   (16 rows x 64 kcols per wave)
    f32x4 sf[4] = {};
#pragma unroll
    for (int kk = 0; kk < 2; ++kk)
#pragma unroll
      for (int n = 0; n < 4; ++n) {
        bf16x8 kf = *(const bf16x8*)&ks[n * 16 + lr][kk * 32 + lk * 8];
        sf[n] = __builtin_amdgcn_mfma_f32_16x16x32_bf16(qf[kk], kf, sf[n], 0, 0, 0);
      }

    if (t == qt) {
#pragma unroll
      for (int n = 0; n < 4; ++n)
#pragma unroll
        for (int r = 0; r < 4; ++r) {
          int kg = t * 64 + n * 16 + lr;
          int qg = qt * 64 + w * 16 + lk * 4 + r;
          if (kg > qg) sf[n][r] = -10000.0f;
        }
    }

    // online softmax; per-row reduce across the 16-lane group
    float pv[4][4];
#pragma unroll
    for (int r = 0; r < 4; ++r) {
      float rm = fmaxf(fmaxf(sf[0][r], sf[1][r]), fmaxf(sf[2][r], sf[3][r]));
#pragma unroll
      for (int off = 1; off < 16; off <<= 1) rm = fmaxf(rm, __shfl_xor(rm, off));
      float mn = fmaxf(mrun[r], rm);
      float sc = __expf(mrun[r] - mn);
      float rs = 0.f;
#pragma unroll
      for (int n = 0; n < 4; ++n) { pv[n][r] = __expf(sf[n][r] - mn); rs += pv[n][r]; }
#pragma unroll
      for (int off = 1; off < 16; off <<= 1) rs += __shfl_xor(rs, off);
      lsum[r] = lsum[r] * sc + rs;
      mrun[r] = mn;
#pragma unroll
      for (int nd = 0; nd < 4; ++nd) o[nd][r] *= sc;
    }

    // P -> LDS (C-layout) -> reload in A-layout (per-wave buffer, in-wave dep)
#pragma unroll
    for (int n = 0; n < 4; ++n)
#pragma unroll
      for (int r = 0; r < 4; ++r)
        ps[w][lk * 4 + r][n * 16 + lr] = f2bf(pv[n][r]);
    bf16x8 pa[2];
#pragma unroll
    for (int kk = 0; kk < 2; ++kk)
      pa[kk] = *(const bf16x8*)&ps[w][lr][kk * 32 + lk * 8];

    // O += P @ V  (B-operand from Vt: col=dcol, contiguous k)
#pragma unroll
    for (int kk = 0; kk < 2; ++kk)
#pragma unroll
      for (int nd = 0; nd < 4; ++nd) {
        bf16x8 vf = *(const bf16x8*)&vts[nd * 16 + lr][kk * 32 + lk * 8];
        o[nd] = __builtin_amdgcn_mfma_f32_16x16x32_bf16(pa[kk], vf, o[nd], 0, 0, 0);
      }
    __syncthreads();
  }

  // epilogue: ctx [B][S][H*D] bf16
  int b = bh >> 4, h = bh & 15;
#pragma unroll
  for (int nd = 0; nd < 4; ++nd)
#pragma unroll
    for (int r = 0; r < 4; ++r) {
      int s = qt * 64 + w * 16 + lk * 4 + r;
      int d = nd * 16 + lr;
      float val = o[nd][r] / lsum[r];
      ctx[((size_t)(b * SQ + s)) * HID + h * 64 + d] = f2bf(val);
    }
}

extern "C" void kernel_launch(void* const* d_in, const int* in_sizes, int n_in,
                              void* d_out, int out_size, void* d_ws, size_t ws_size,
                              hipStream_t stream) {
  const float* hs   = (const float*)d_in[0];
  const float* wqkv = (const float*)d_in[1];
  const float* bqkv = (const float*)d_in[2];
  const float* wd   = (const float*)d_in[3];
  const float* bd   = (const float*)d_in[4];
  float* out = (float*)d_out;
  char* ws = (char*)d_ws;
  const size_t MB = 1u << 20;

  short* hs_bf  = (short*)(ws);            // 16 MB: [8192][1024] bf16
  short* wqkv_t = (short*)(ws + 16 * MB);  //  6 MB: [3072][1024] bf16
  short* wd_t   = (short*)(ws + 22 * MB);  //  2 MB: [1024][1024] bf16
  short* qbuf   = (short*)(ws + 24 * MB);  // 16 MB: [64][2048][64]
  short* kbuf   = (short*)(ws + 40 * MB);  // 16 MB: [64][2048][64]
  short* vtbuf  = (short*)(ws + 56 * MB);  // 16 MB: [64][64][2048]
  short* ctx    = (short*)(ws + 72 * MB);  // 16 MB: [8192][1024]

  k_cvt<<<8192, 256, 0, stream>>>(hs, hs_bf, MTOK * HID / 4);
  k_tr<<<dim3(96, 32), dim3(32, 8), 0, stream>>>(wqkv, wqkv_t, 1024, 3072);
  k_tr<<<dim3(32, 32), dim3(32, 8), 0, stream>>>(wd, wd_t, 1024, 1024);
  k_gemm<0><<<dim3(24, 64), 256, 0, stream>>>(hs_bf, wqkv_t, bqkv,
                                              qbuf, kbuf, vtbuf, nullptr, 1024);
  k_attn<<<dim3(32, 64), 256, 0, stream>>>(qbuf, kbuf, vtbuf, ctx);
  k_gemm<1><<<dim3(8, 64), 256, 0, stream>>>(ctx, wd_t, bd,
                                             nullptr, nullptr, nullptr, out, 1024);
}

// Round 2
// 211.460 us; speedup vs baseline: 2.0507x; 2.0507x over previous
//
#include <hip/hip_runtime.h>

#define H_NUM 16
#define HD    64
#define SQ    2048
#define HID   1024
#define MTOK  8192   // B*S

typedef __attribute__((ext_vector_type(8))) short bf16x8;
typedef __attribute__((ext_vector_type(4))) short s16x4;
typedef __attribute__((ext_vector_type(4))) float f32x4;

__device__ __forceinline__ short f2bf(float f) {
  union { float f; unsigned u; } v; v.f = f;
  unsigned r = v.u + 0x7fffu + ((v.u >> 16) & 1u);
  return (short)(r >> 16);
}

__device__ __forceinline__ float fexp2(float x) {
#if __has_builtin(__builtin_amdgcn_exp2f)
  return __builtin_amdgcn_exp2f(x);
#else
  return exp2f(x);
#endif
}

__device__ __forceinline__ void gload_lds16(const short* g, short* l) {
  __builtin_amdgcn_global_load_lds(
      (const __attribute__((address_space(1))) void*)g,
      (__attribute__((address_space(3))) void*)l, 16, 0, 0);
}

// ---------- converters ----------
__global__ void k_cvt(const float* __restrict__ in, short* __restrict__ out, int n4) {
  int i = blockIdx.x * blockDim.x + threadIdx.x;
  if (i < n4) {
    float4 f = ((const float4*)in)[i];
    s16x4 o = { f2bf(f.x), f2bf(f.y), f2bf(f.z), f2bf(f.w) };
    ((s16x4*)out)[i] = o;
  }
}

// out[c][r] = bf16(in[r][c]);  R,C multiples of 32; block (32,8)
__global__ void k_tr(const float* __restrict__ in, short* __restrict__ out, int R, int C) {
  __shared__ float t[32][33];
  int c0 = blockIdx.x * 32, r0 = blockIdx.y * 32;
  int tx = threadIdx.x, ty = threadIdx.y;
#pragma unroll
  for (int i = 0; i < 4; i++)
    t[ty + 8 * i][tx] = in[(size_t)(r0 + ty + 8 * i) * C + c0 + tx];
  __syncthreads();
#pragma unroll
  for (int i = 0; i < 4; i++)
    out[(size_t)(c0 + ty + 8 * i) * R + r0 + tx] = f2bf(t[tx][ty + 8 * i]);
}

// ---------- GEMM: C[M,N] = A[M,K] @ Bt[N,K]^T + bias ----------
// EPI=0: scatter into k/vt/q buffers (col order: k, v, q; q pre-scaled by 0.125*log2e)
// EPI=1: f32 out with bias
template <int EPI>
__global__ __launch_bounds__(256) void k_gemm(
    const short* __restrict__ A, const short* __restrict__ Bt,
    const float* __restrict__ bias,
    short* __restrict__ qbuf, short* __restrict__ kbuf, short* __restrict__ vtbuf,
    float* __restrict__ outf, int Kd) {
  __shared__ short as[128][64];
  __shared__ short bs[128][64];
  const int tid = threadIdx.x;
  const int w = tid >> 6, l = tid & 63;
  const int lr = l & 15, lk = l >> 4;
  const int wr = w >> 1, wc = w & 1;
  const int m0 = blockIdx.y * 128, n0 = blockIdx.x * 128;

  f32x4 acc[4][4] = {};

  for (int kt = 0; kt < Kd; kt += 64) {
#pragma unroll
    for (int rnd = 0; rnd < 4; ++rnd) {
      int e = rnd * 2048 + w * 512 + l * 8;
      int row = e >> 6, col = e & 63;
      gload_lds16(A + (size_t)(m0 + row) * Kd + kt + col,
                  &as[0][0] + rnd * 2048 + w * 512);
      gload_lds16(Bt + (size_t)(n0 + row) * Kd + kt + col,
                  &bs[0][0] + rnd * 2048 + w * 512);
    }
    __syncthreads();
#pragma unroll
    for (int kk = 0; kk < 2; ++kk) {
      bf16x8 af[4], bf[4];
#pragma unroll
      for (int m = 0; m < 4; ++m)
        af[m] = *(const bf16x8*)&as[wr * 64 + m * 16 + lr][kk * 32 + lk * 8];
#pragma unroll
      for (int n = 0; n < 4; ++n)
        bf[n] = *(const bf16x8*)&bs[wc * 64 + n * 16 + lr][kk * 32 + lk * 8];
#pragma unroll
      for (int m = 0; m < 4; ++m)
#pragma unroll
        for (int n = 0; n < 4; ++n)
          acc[m][n] = __builtin_amdgcn_mfma_f32_16x16x32_bf16(af[m], bf[n], acc[m][n], 0, 0, 0);
    }
    __syncthreads();
  }

  // C layout: col=lane&15, row=(lane>>4)*4+reg  [m89]
  const float SCLQ = 0.125f * 1.44269504088896341f;
#pragma unroll
  for (int n = 0; n < 4; ++n) {
    const int col = n0 + wc * 64 + n * 16 + lr;
    const float bv = bias[col];
    if (EPI == 1) {
#pragma unroll
      for (int m = 0; m < 4; ++m) {
        int row = m0 + wr * 64 + m * 16 + lk * 4;
#pragma unroll
        for (int r = 0; r < 4; ++r)
          outf[(size_t)(row + r) * HID + col] = acc[m][n][r] + bv;
      }
    } else if (col < HID) {  // K: [BH][S][D]
      int h = col >> 6, d = col & 63;
#pragma unroll
      for (int m = 0; m < 4; ++m) {
        int row = m0 + wr * 64 + m * 16 + lk * 4;
        int b = row >> 11, s = row & 2047;
#pragma unroll
        for (int r = 0; r < 4; ++r)
          kbuf[((size_t)(b * H_NUM + h) * SQ + s + r) * HD + d] = f2bf(acc[m][n][r] + bv);
      }
    } else if (col < 2 * HID) {  // V transposed: [BH][D][S], pack 4 s per store
      int f = col - HID, h = f >> 6, d = f & 63;
#pragma unroll
      for (int m = 0; m < 4; ++m) {
        int row = m0 + wr * 64 + m * 16 + lk * 4;
        int b = row >> 11, s = row & 2047;
        s16x4 pk;
#pragma unroll
        for (int r = 0; r < 4; ++r) pk[r] = f2bf(acc[m][n][r] + bv);
        *(s16x4*)&vtbuf[((size_t)(b * H_NUM + h) * HD + d) * SQ + s] = pk;
      }
    } else {  // Q: [BH][S][D], scaled into exp2 domain
      int f = col - 2 * HID, h = f >> 6, d = f & 63;
#pragma unroll
      for (int m = 0; m < 4; ++m) {
        int row = m0 + wr * 64 + m * 16 + lk * 4;
        int b = row >> 11, s = row & 2047;
#pragma unroll
        for (int r = 0; r < 4; ++r)
          qbuf[((size_t)(b * H_NUM + h) * SQ + s + r) * HD + d] = f2bf((acc[m][n][r] + bv) * SCLQ);
      }
    }
  }
}

// ---------- flash attention, causal, balanced pairs ----------
// grid: (8, B*H), block 512 (8 waves x 16 q-rows = 128-row q-tile).
// Block handles q-tiles {a, 15-a}: exactly 34 K-tile iterations each.
// K/V double-buffered in LDS, XOR-swizzled (pre-swizzled gload source).
__global__ __launch_bounds__(512) void k_attn(
    const short* __restrict__ Q, const short* __restrict__ K,
    const short* __restrict__ Vt, short* __restrict__ ctx) {
  __shared__ short ks[2][4096];
  __shared__ short vs[2][4096];
  __shared__ short ps[8][16][72];  // per-wave P buffer, 144B rows (16B-aligned, conflict-lite)
  const int tid = threadIdx.x;
  const int w = tid >> 6, l = tid & 63;
  const int lr = l & 15, lk = l >> 4;
  const int bh = blockIdx.y;
  const int bb = bh >> 4, hh = bh & 15;
  const size_t base = (size_t)bh * (SQ * HD);

  // staging: thread owns one 16B granule; source column pre-swizzled
  const int srow = tid >> 3;                              // 0..63
  const int scol = ((tid & 7) * 8) ^ ((srow & 7) * 8);    // swizzled element col
  const short* kg0 = K + base + srow * HD + scol;         // + t*4096
  const short* vg0 = Vt + base + (size_t)srow * SQ + scol;  // + t*64
  short* kld = &ks[0][0] + tid * 8;
  short* vld = &vs[0][0] + tid * 8;
  const int rdswz = (lr & 7) * 8;  // read-side swizzle (row = *16 + lr)

  int buf = 0;
  for (int pass = 0; pass < 2; ++pass) {
    const int qt = pass ? (15 - blockIdx.x) : blockIdx.x;
    const int nt = 2 * qt + 2;
    const int diag = 2 * qt + (w >> 2);   // wave-uniform diagonal tile
    const int qr = qt * 128 + w * 16;

    bf16x8 qf[2];
#pragma unroll
    for (int kk = 0; kk < 2; ++kk)
      qf[kk] = *(const bf16x8*)(Q + base + (size_t)(qr + lr) * HD + kk * 32 + lk * 8);

    f32x4 o[4] = {};
    float mrun[4], lsum[4];
#pragma unroll
    for (int r = 0; r < 4; ++r) { mrun[r] = -3.0e4f; lsum[r] = 0.f; }

    // prologue: stage tile 0
    gload_lds16(kg0, kld + buf * 4096);
    gload_lds16(vg0, vld + buf * 4096);
    __syncthreads();

    for (int t = 0; t < nt; ++t) {
      if (t + 1 < nt) {  // stage next tile into other buffer (overlaps compute)
        gload_lds16(kg0 + (t + 1) * 4096, kld + (buf ^ 1) * 4096);
        gload_lds16(vg0 + (t + 1) * 64, vld + (buf ^ 1) * 4096);
      }
      if (t <= diag) {
        const short* kb = &ks[buf][0];
        const short* vb = &vs[buf][0];
        // S' = (Q*log2e/8) @ K^T
        f32x4 sf[4] = {};
#pragma unroll
        for (int kk = 0; kk < 2; ++kk)
#pragma unroll
          for (int n = 0; n < 4; ++n) {
            bf16x8 kf = *(const bf16x8*)(kb + (n * 16 + lr) * 64 + ((kk * 32 + lk * 8) ^ rdswz));
            sf[n] = __builtin_amdgcn_mfma_f32_16x16x32_bf16(qf[kk], kf, sf[n], 0, 0, 0);
          }
        if (t == diag) {
          const int qg = qr + lk * 4;
#pragma unroll
          for (int n = 0; n < 4; ++n) {
            int kg = t * 64 + n * 16 + lr;
#pragma unroll
            for (int r = 0; r < 4; ++r)
              if (kg > qg + r) sf[n][r] = -14426.95f;  // -10000 * log2(e)
          }
        }
        // online softmax (exp2 domain); lsum kept as per-lane partial
        float sc[4];
#pragma unroll
        for (int r = 0; r < 4; ++r) {
          float rm = fmaxf(fmaxf(sf[0][r], sf[1][r]), fmaxf(sf[2][r], sf[3][r]));
#pragma unroll
          for (int off = 1; off < 16; off <<= 1) rm = fmaxf(rm, __shfl_xor(rm, off));
          float mn = fmaxf(mrun[r], rm);
          sc[r] = fexp2(mrun[r] - mn);
          mrun[r] = mn;
          float rs = 0.f;
#pragma unroll
          for (int n = 0; n < 4; ++n) {
            float p = fexp2(sf[n][r] - mn);
            rs += p;
            ps[w][lk * 4 + r][n * 16 + lr] = (short)(__float_as_uint(p) >> 16);
          }
          lsum[r] = lsum[r] * sc[r] + rs;
        }
#pragma unroll
        for (int nd = 0; nd < 4; ++nd)
#pragma unroll
          for (int r = 0; r < 4; ++r) o[nd][r] *= sc[r];
        // P back as A-fragment (per-wave buffer, same-wave dependency)
        bf16x8 pa[2];
#pragma unroll
        for (int kk = 0; kk < 2; ++kk)
          pa[kk] = *(const bf16x8*)&ps[w][lr][kk * 32 + lk * 8];
        // O += P @ V
#pragma unroll
        for (int kk = 0; kk < 2; ++kk)
#pragma unroll
          for (int nd = 0; nd < 4; ++nd) {
            bf16x8 vf = *(const bf16x8*)(vb + (nd * 16 + lr) * 64 + ((kk * 32 + lk * 8) ^ rdswz));
            o[nd] = __builtin_amdgcn_mfma_f32_16x16x32_bf16(pa[kk], vf, o[nd], 0, 0, 0);
          }
      }
      __syncthreads();  // drains staging vmcnt + protects buf swap
      buf ^= 1;
    }

    // epilogue: reduce lsum across the 16 row-lanes, write ctx
    float inv[4];
#pragma unroll
    for (int r = 0; r < 4; ++r) {
      float tot = lsum[r];
#pragma unroll
      for (int off = 1; off < 16; off <<= 1) tot += __shfl_xor(tot, off);
      inv[r] = 1.0f / tot;
    }
#pragma unroll
    for (int nd = 0; nd < 4; ++nd)
#pragma unroll
      for (int r = 0; r < 4; ++r) {
        int s = qr + lk * 4 + r;
        ctx[((size_t)(bb * SQ + s)) * HID + hh * 64 + nd * 16 + lr] = f2bf(o[nd][r] * inv[r]);
      }
  }
}

extern "C" void kernel_launch(void* const* d_in, const int* in_sizes, int n_in,
                              void* d_out, int out_size, void* d_ws, size_t ws_size,
                              hipStream_t stream) {
  const float* hs   = (const float*)d_in[0];
  const float* wqkv = (const float*)d_in[1];
  const float* bqkv = (const float*)d_in[2];
  const float* wd   = (const float*)d_in[3];
  const float* bd   = (const float*)d_in[4];
  float* out = (float*)d_out;
  char* ws = (char*)d_ws;
  const size_t MB = 1u << 20;

  short* hs_bf  = (short*)(ws);            // 16 MB: [8192][1024] bf16
  short* wqkv_t = (short*)(ws + 16 * MB);  //  6 MB: [3072][1024] bf16
  short* wd_t   = (short*)(ws + 22 * MB);  //  2 MB: [1024][1024] bf16
  short* qbuf   = (short*)(ws + 24 * MB);  // 16 MB: [64][2048][64]
  short* kbuf   = (short*)(ws + 40 * MB);  // 16 MB: [64][2048][64]
  short* vtbuf  = (short*)(ws + 56 * MB);  // 16 MB: [64][64][2048]
  short* ctx    = (short*)(ws + 72 * MB);  // 16 MB: [8192][1024]

  k_cvt<<<8192, 256, 0, stream>>>(hs, hs_bf, MTOK * HID / 4);
  k_tr<<<dim3(96, 32), dim3(32, 8), 0, stream>>>(wqkv, wqkv_t, 1024, 3072);
  k_tr<<<dim3(32, 32), dim3(32, 8), 0, stream>>>(wd, wd_t, 1024, 1024);
  k_gemm<0><<<dim3(24, 64), 256, 0, stream>>>(hs_bf, wqkv_t, bqkv,
                                              qbuf, kbuf, vtbuf, nullptr, 1024);
  k_attn<<<dim3(8, 64), 512, 0, stream>>>(qbuf, kbuf, vtbuf, ctx);
  k_gemm<1><<<dim3(8, 64), 256, 0, stream>>>(ctx, wd_t, bd,
                                             nullptr, nullptr, nullptr, out, 1024);
}